// Round 11
// baseline (598.479 us; speedup 1.0000x reference)
//
#include <hip/hip_runtime.h>

// Transducer joint: out[b,t,u,o] = leaky_relu(tn_proj[b,t,o] + pn_proj[b,u,o] + bias[o])
// Shapes: B=8, T=300, U=80, H=512, O=640.
// Stage 1: fused dual GEMM -> tn_proj (2400x640), pn_proj (640x640, bias folded).
// Stage 2: broadcast add + leaky_relu, write-bound (491.5 MB, floor ~79 us @6.25 TB/s).
//
// R7 change (GEMM ONLY; joint kernel byte-identical to R6): single-wave 64x64
// tile with 8x8 register blocking. Old 4x4/256-thr tile needed 2 ds_read_b128
// per 16 FMA-inst -> LDS-return-BW-bound ~2-3x (m134: b128 ~8-12cyc, 128B/cyc
// per CU). New: 4 b128 per 64 FMA-inst, and single wave/block -> no barriers.

#define DIM_H 512
#define DIM_O 640
#define DIM_B 8
#define DIM_T 300
#define DIM_U 80
#define M_TN  2400   // B*T
#define M_PN  640    // B*U
#define NEG_SLOPE 0.01f

#define NB_N 10                            // 640/64 column blocks
#define NB_TN 380                          // ceil(2400/64)=38 row blocks * 10
#define NB_PN 100                          // 640/64=10 row blocks * 10

typedef float f32x4 __attribute__((ext_vector_type(4)));

__global__ __launch_bounds__(64) void proj_gemm(
    const float* __restrict__ tn_in,
    const float* __restrict__ pn_in,
    const float* __restrict__ W,
    const float* __restrict__ bias,
    float* __restrict__ tn_out,
    float* __restrict__ pn_out)
{
    const int bid = blockIdx.x;
    const float* A; const float* Wp; float* Cout; int M; bool addb; int local;
    if (bid < NB_TN) {
        A = tn_in; Wp = W;                 Cout = tn_out; M = M_TN; addb = false; local = bid;
    } else {
        A = pn_in; Wp = W + DIM_H * DIM_O; Cout = pn_out; M = M_PN; addb = true;  local = bid - NB_TN;
    }
    const int bm = local / NB_N;
    const int bn = local - bm * NB_N;
    const int row0 = bm * 64;
    const int col0 = bn * 64;

    // As transposed [k][row] (+4 pad: scalar transpose-writes land 8-way worst
    // case, ~100cy per K-step vs 4096cy FMA - negligible; reads 2-way = free).
    __shared__ float As[32][68];
    __shared__ float Bs[32][64];

    const int tid = threadIdx.x;        // 0..63, exactly one wave
    const int ty = tid >> 3;            // compute: rows ty*8..+7
    const int tx = tid & 7;             // compute: cols tx*8..+7
    const int lrow = (tid & 7) * 8;     // A-load: this thread's 8 rows
    const int lkg  = (tid >> 3) * 4;    // A-load: k sub-offset 0,4..28
    const int bkr  = tid >> 4;          // B-load: k sub-row 0..3
    const int bcol = (tid & 15) * 4;    // B-load: col offset 0..60

    bool rok[8];
    #pragma unroll
    for (int j = 0; j < 8; ++j) rok[j] = (row0 + lrow + j) < M;

    float acc[8][8];
    #pragma unroll
    for (int i = 0; i < 8; ++i)
        #pragma unroll
        for (int j = 0; j < 8; ++j) acc[i][j] = 0.f;

    const f32x4 fz = 0.f;
    f32x4 av[8], bv[8];
    #pragma unroll
    for (int j = 0; j < 8; ++j) {
        av[j] = rok[j] ? *(const f32x4*)(A + (size_t)(row0 + lrow + j) * DIM_H + lkg) : fz;
        bv[j] = *(const f32x4*)(Wp + (size_t)(4 * j + bkr) * DIM_O + col0 + bcol);
    }

    for (int k0 = 0; k0 < DIM_H; k0 += 32) {
        // current tile regs -> LDS (in-wave lgkmcnt orders vs last iter's reads;
        // no __syncthreads needed with a single wave)
        #pragma unroll
        for (int j = 0; j < 8; ++j) {
            #pragma unroll
            for (int c = 0; c < 4; ++c) As[lkg + c][lrow + j] = av[j][c];
            *(f32x4*)&Bs[4 * j + bkr][bcol] = bv[j];
        }
        // prefetch next K-tile; ~600cy VMEM latency hides under 2048 FMAs
        const int kn = k0 + 32;
        if (kn < DIM_H) {
            #pragma unroll
            for (int j = 0; j < 8; ++j) {
                av[j] = rok[j] ? *(const f32x4*)(A + (size_t)(row0 + lrow + j) * DIM_H + kn + lkg) : fz;
                bv[j] = *(const f32x4*)(Wp + (size_t)(kn + 4 * j + bkr) * DIM_O + col0 + bcol);
            }
        }
        // compute: 32 kk x 64 FMA, k-ascending per output (bitwise-stable absmax)
        #pragma unroll 16
        for (int kk = 0; kk < 32; ++kk) {
            const f32x4 a0 = *(const f32x4*)&As[kk][ty * 8];
            const f32x4 a1 = *(const f32x4*)&As[kk][ty * 8 + 4];
            const f32x4 b0 = *(const f32x4*)&Bs[kk][tx * 8];
            const f32x4 b1 = *(const f32x4*)&Bs[kk][tx * 8 + 4];
            #pragma unroll
            for (int i = 0; i < 4; ++i) {
                #pragma unroll
                for (int j = 0; j < 4; ++j) {
                    acc[i][j]         = fmaf(a0[i], b0[j], acc[i][j]);
                    acc[i][j + 4]     = fmaf(a0[i], b1[j], acc[i][j + 4]);
                    acc[i + 4][j]     = fmaf(a1[i], b0[j], acc[i + 4][j]);
                    acc[i + 4][j + 4] = fmaf(a1[i], b1[j], acc[i + 4][j + 4]);
                }
            }
        }
    }

    f32x4 bs0 = fz, bs1 = fz;
    if (addb) {
        bs0 = *(const f32x4*)(bias + col0 + tx * 8);
        bs1 = *(const f32x4*)(bias + col0 + tx * 8 + 4);
    }
    #pragma unroll
    for (int i = 0; i < 8; ++i) {
        const int r = row0 + ty * 8 + i;
        if (r < M) {
            f32x4 v0, v1;
            #pragma unroll
            for (int j = 0; j < 4; ++j) {
                v0[j] = acc[i][j] + bs0[j];
                v1[j] = acc[i][j + 4] + bs1[j];
            }
            float* dst = Cout + (size_t)r * DIM_O + col0 + tx * 8;
            *(f32x4*)dst       = v0;
            *(f32x4*)(dst + 4) = v1;
        }
    }
}

// Broadcast + leaky_relu. One block per (b,t) row, 640 threads.
// Thread owns a fixed output column group o4 = tid%160; tn value lives in a
// register; u strided by 4 -> idx += 640, zero per-iter index math, 20 iters.
// Output stores are nontemporal: 491.5 MB of streaming writes must not evict
// the pn panels (1.64 MB, re-read by every block) from L2.
// (BYTE-IDENTICAL to R6 - this round is a GEMM-only experiment.)
__global__ __launch_bounds__(640) void joint_kernel(
    const float* __restrict__ tn_proj,   // M_TN x O
    const float* __restrict__ pn_proj,   // M_PN x O (bias pre-added)
    float* __restrict__ out)             // [bt][u][o]
{
    const int bt = blockIdx.x;           // 0..2399
    const int b = bt / DIM_T;
    const int tid = threadIdx.x;

    __shared__ f32x4 tns[DIM_O / 4];     // 160 f32x4 = 2.56 KB
    if (tid < DIM_O / 4)
        tns[tid] = ((const f32x4*)(tn_proj + (size_t)bt * DIM_O))[tid];
    __syncthreads();

    const int o4 = tid % (DIM_O / 4);    // fixed column group per thread
    const f32x4 t = tns[o4];

    const f32x4* __restrict__ pn4 = (const f32x4*)(pn_proj + (size_t)b * DIM_U * DIM_O);
    f32x4* __restrict__ out4 = (f32x4*)(out + (size_t)bt * DIM_U * DIM_O);

    #pragma unroll 4
    for (int idx = tid; idx < DIM_U * (DIM_O / 4); idx += 640) {
        const f32x4 p = pn4[idx];
        f32x4 r;
        #pragma unroll
        for (int j = 0; j < 4; ++j) {
            const float x = t[j] + p[j];
            r[j] = fmaxf(x, 0.f) + NEG_SLOPE * fminf(x, 0.f);
        }
        __builtin_nontemporal_store(r, &out4[idx]);
    }
}

extern "C" void kernel_launch(void* const* d_in, const int* in_sizes, int n_in,
                              void* d_out, int out_size, void* d_ws, size_t ws_size,
                              hipStream_t stream) {
    const float* tn   = (const float*)d_in[0];   // (8,300,1,512)
    const float* pn   = (const float*)d_in[1];   // (8,1,80,512)
    const float* W    = (const float*)d_in[2];   // (1024,640)
    const float* bias = (const float*)d_in[3];   // (640,)
    float* out = (float*)d_out;

    float* tn_proj = (float*)d_ws;                       // 2400*640 fp32 = 6.14 MB
    float* pn_proj = tn_proj + (size_t)M_TN * DIM_O;     // 640*640 fp32 = 1.64 MB

    proj_gemm<<<NB_TN + NB_PN, 64, 0, stream>>>(tn, pn, W, bias, tn_proj, pn_proj);
    joint_kernel<<<M_TN, 640, 0, stream>>>(tn_proj, pn_proj, out);
}

// Round 13
// 538.979 us; speedup vs baseline: 1.1104x; 1.1104x over previous
//
#include <hip/hip_runtime.h>

// Transducer joint: out[b,t,u,o] = leaky_relu(tn_proj[b,t,o] + pn_proj[b,u,o] + bias[o])
// B=8, T=300, U=80, H=512, O=640.
//
// R12 structure (fusion): 
//   K1 pn_gemm: pn_proj(640x640) = PN*W[512:]+bias, plain stores (stay L2-resident).
//   K2 tn_joint: R6-proven 64x64/256thr/BK32 GEMM computes tn tile in regs, then the
//      epilogue loops u=0..79 reading pn_proj from L2 and NT-streams lrelu(tn+pn)
//      directly to out (1.3 MB/block). tn_proj never materialized/re-read; one fewer
//      serial dispatch. Per-element arithmetic identical to R6 -> absmax 0.0.
// R11 lesson: single-wave GEMM regressed +76us (480 waves on 1024 SIMDs, no
// intra-CU wave overlap to hide LDS latency). Multi-wave R6 GEMM form restored.

#define DIM_H 512
#define DIM_O 640
#define DIM_T 300
#define DIM_U 80
#define M_TN  2400
#define M_PN  640
#define NEG_SLOPE 0.01f
#define BK 32

typedef float f32x4 __attribute__((ext_vector_type(4)));

// K1: pn_proj = PN * W[512:] + bias. 640x640, 100 blocks of 64x64. Exact R6 GEMM
// structure; no row masking (640 % 64 == 0). Plain stores: result re-read by K2.
__global__ __launch_bounds__(256, 2) void pn_gemm(
    const float* __restrict__ pn_in,
    const float* __restrict__ W,
    const float* __restrict__ bias,
    float* __restrict__ pn_out)
{
    const int bm = blockIdx.x / 10;
    const int bn = blockIdx.x - bm * 10;
    const int row0 = bm * 64, col0 = bn * 64;
    const float* __restrict__ Wp = W + DIM_H * DIM_O;

    __shared__ float As[BK][68];   // transposed [k][row], pad 68 (2-way = free)
    __shared__ float Bs[BK][64];

    const int tid = threadIdx.x;
    const int ty = tid >> 4, tx = tid & 15;
    const int ar = tid >> 2, ac = (tid & 3) << 3;
    const int br = tid >> 3, bc = (tid & 7) << 3;

    float acc[4][4];
    #pragma unroll
    for (int i = 0; i < 4; ++i)
        #pragma unroll
        for (int j = 0; j < 4; ++j) acc[i][j] = 0.f;

    const float* __restrict__ Arow = pn_in + (size_t)(row0 + ar) * DIM_H;
    const float* __restrict__ Bbase = Wp + col0;

    f32x4 a0 = *(const f32x4*)(Arow + ac);
    f32x4 a1 = *(const f32x4*)(Arow + ac + 4);
    f32x4 b0 = *(const f32x4*)(Bbase + (size_t)br * DIM_O + bc);
    f32x4 b1 = *(const f32x4*)(Bbase + (size_t)br * DIM_O + bc + 4);

    for (int k0 = 0; k0 < DIM_H; k0 += BK) {
        __syncthreads();
        #pragma unroll
        for (int j = 0; j < 4; ++j) {
            As[ac + j][ar]     = a0[j];
            As[ac + 4 + j][ar] = a1[j];
        }
        *(f32x4*)&Bs[br][bc]     = b0;
        *(f32x4*)&Bs[br][bc + 4] = b1;
        __syncthreads();

        const int kn = k0 + BK;
        if (kn < DIM_H) {
            a0 = *(const f32x4*)(Arow + kn + ac);
            a1 = *(const f32x4*)(Arow + kn + ac + 4);
            b0 = *(const f32x4*)(Bbase + (size_t)(kn + br) * DIM_O + bc);
            b1 = *(const f32x4*)(Bbase + (size_t)(kn + br) * DIM_O + bc + 4);
        }

        #pragma unroll
        for (int kk = 0; kk < BK; ++kk) {
            const f32x4 a = *(const f32x4*)&As[kk][ty << 2];
            const f32x4 b = *(const f32x4*)&Bs[kk][tx << 2];
            #pragma unroll
            for (int i = 0; i < 4; ++i) {
                acc[i][0] = fmaf(a[i], b[0], acc[i][0]);
                acc[i][1] = fmaf(a[i], b[1], acc[i][1]);
                acc[i][2] = fmaf(a[i], b[2], acc[i][2]);
                acc[i][3] = fmaf(a[i], b[3], acc[i][3]);
            }
        }
    }

    const f32x4 bsv = *(const f32x4*)(bias + col0 + (tx << 2));
    #pragma unroll
    for (int i = 0; i < 4; ++i) {
        f32x4 v;
        #pragma unroll
        for (int j = 0; j < 4; ++j) v[j] = acc[i][j] + bsv[j];
        *(f32x4*)(pn_out + (size_t)(row0 + (ty << 2) + i) * DIM_O + col0 + (tx << 2)) = v;
    }
}

// K2: tn GEMM (R6 structure, Wt = W[:512]) fused with the broadcast+lrelu epilogue.
// Each block owns (64 bt-rows x 64 o-cols); epilogue streams 64x80x64 outputs.
__global__ __launch_bounds__(256, 2) void tn_joint(
    const float* __restrict__ tn_in,
    const float* __restrict__ W,
    const float* __restrict__ pn_proj,   // bias pre-added
    float* __restrict__ out)
{
    const int bm = blockIdx.x / 10;
    const int bn = blockIdx.x - bm * 10;
    const int row0 = bm * 64, col0 = bn * 64;

    __shared__ float As[BK][68];
    __shared__ float Bs[BK][64];

    const int tid = threadIdx.x;
    const int ty = tid >> 4, tx = tid & 15;
    const int ar = tid >> 2, ac = (tid & 3) << 3;
    const int br = tid >> 3, bc = (tid & 7) << 3;

    float acc[4][4];
    #pragma unroll
    for (int i = 0; i < 4; ++i)
        #pragma unroll
        for (int j = 0; j < 4; ++j) acc[i][j] = 0.f;

    const int gr = row0 + ar;
    const bool arow_ok = (gr < M_TN);
    const float* __restrict__ Arow = tn_in + (size_t)gr * DIM_H;
    const float* __restrict__ Bbase = W + col0;

    const f32x4 fz = 0.f;
    f32x4 a0 = fz, a1 = fz, b0, b1;
    if (arow_ok) {
        a0 = *(const f32x4*)(Arow + ac);
        a1 = *(const f32x4*)(Arow + ac + 4);
    }
    b0 = *(const f32x4*)(Bbase + (size_t)br * DIM_O + bc);
    b1 = *(const f32x4*)(Bbase + (size_t)br * DIM_O + bc + 4);

    for (int k0 = 0; k0 < DIM_H; k0 += BK) {
        __syncthreads();
        #pragma unroll
        for (int j = 0; j < 4; ++j) {
            As[ac + j][ar]     = a0[j];
            As[ac + 4 + j][ar] = a1[j];
        }
        *(f32x4*)&Bs[br][bc]     = b0;
        *(f32x4*)&Bs[br][bc + 4] = b1;
        __syncthreads();

        const int kn = k0 + BK;
        if (kn < DIM_H) {
            if (arow_ok) {
                a0 = *(const f32x4*)(Arow + kn + ac);
                a1 = *(const f32x4*)(Arow + kn + ac + 4);
            }
            b0 = *(const f32x4*)(Bbase + (size_t)(kn + br) * DIM_O + bc);
            b1 = *(const f32x4*)(Bbase + (size_t)(kn + br) * DIM_O + bc + 4);
        }

        #pragma unroll
        for (int kk = 0; kk < BK; ++kk) {
            const f32x4 a = *(const f32x4*)&As[kk][ty << 2];
            const f32x4 b = *(const f32x4*)&Bs[kk][tx << 2];
            #pragma unroll
            for (int i = 0; i < 4; ++i) {
                acc[i][0] = fmaf(a[i], b[0], acc[i][0]);
                acc[i][1] = fmaf(a[i], b[1], acc[i][1]);
                acc[i][2] = fmaf(a[i], b[2], acc[i][2]);
                acc[i][3] = fmaf(a[i], b[3], acc[i][3]);
            }
        }
    }

    // Fused joint epilogue: thread owns 4 bt-rows x 4 o-cols of tn in registers.
    // For each row: b = r/300 (rows may span batches within a tile), read the
    // pn panel row from L2 (1.64 MB total, fits every XCD's L2), NT-stream out.
    // Wave stores: 16 lanes x 16B = 256B contiguous per row-group - coalesced.
    #pragma unroll
    for (int i = 0; i < 4; ++i) {
        const int r = row0 + (ty << 2) + i;
        if (r < M_TN) {
            const int b = r / DIM_T;
            f32x4 tv;
            #pragma unroll
            for (int j = 0; j < 4; ++j) tv[j] = acc[i][j];
            const float* __restrict__ pbase =
                pn_proj + (size_t)b * (DIM_U * DIM_O) + col0 + (tx << 2);
            float* __restrict__ obase =
                out + (size_t)r * (DIM_U * DIM_O) + col0 + (tx << 2);
            #pragma unroll 4
            for (int u = 0; u < DIM_U; ++u) {
                const f32x4 p = *(const f32x4*)(pbase + (size_t)u * DIM_O);
                f32x4 v;
                #pragma unroll
                for (int j = 0; j < 4; ++j) {
                    const float x = tv[j] + p[j];
                    v[j] = fmaxf(x, 0.f) + NEG_SLOPE * fminf(x, 0.f);
                }
                __builtin_nontemporal_store(v, (f32x4*)(obase + (size_t)u * DIM_O));
            }
        }
    }
}

extern "C" void kernel_launch(void* const* d_in, const int* in_sizes, int n_in,
                              void* d_out, int out_size, void* d_ws, size_t ws_size,
                              hipStream_t stream) {
    const float* tn   = (const float*)d_in[0];   // (8,300,1,512)
    const float* pn   = (const float*)d_in[1];   // (8,1,80,512)
    const float* W    = (const float*)d_in[2];   // (1024,640)
    const float* bias = (const float*)d_in[3];   // (640,)
    float* out = (float*)d_out;

    float* pn_proj = (float*)d_ws;               // 640*640 fp32 = 1.64 MB

    pn_gemm<<<100, 256, 0, stream>>>(pn, W, bias, pn_proj);
    tn_joint<<<380, 256, 0, stream>>>(tn, W, pn_proj, out);
}

// Round 16
// 523.221 us; speedup vs baseline: 1.1438x; 1.0301x over previous
//
#include <hip/hip_runtime.h>

// Transducer joint: out[b,t,u,o] = leaky_relu(tn_proj[b,t,o] + pn_proj[b,u,o] + bias[o])
// B=8, T=300, U=80, H=512, O=640.
// R14: GEMM = exact R6 proj_gemm (480 blocks, 256 thr, BK32, prefetch).
//      Joint = grid-stride, fully-resident (2048 blk x 256 thr = 8 blk/CU), no LDS,
//      58-59 iters/thread exactly -> zero dispatch tail (R6 joint: 2400 blocks =
//      3.125 rounds at 3 blk/CU -> ~30us tail; R12: 380 blocks -> 2x tail, +16us).

#define DIM_H 512
#define DIM_O 640
#define DIM_T 300
#define DIM_U 80
#define M_TN  2400
#define M_PN  640
#define NEG_SLOPE 0.01f
#define BK 32
#define NB_N 10
#define NB_TN 380
#define NB_PN 100

typedef float f32x4 __attribute__((ext_vector_type(4)));

// Fused dual projection GEMM - byte-identical to R6. Blocks [0,380): tn_proj;
// [380,480): pn_proj (bias folded).
__global__ __launch_bounds__(256, 2) void proj_gemm(
    const float* __restrict__ tn_in,
    const float* __restrict__ pn_in,
    const float* __restrict__ W,
    const float* __restrict__ bias,
    float* __restrict__ tn_out,
    float* __restrict__ pn_out)
{
    const int bid = blockIdx.x;
    const float* A; const float* Wp; float* Cout; int M; bool addb; int local;
    if (bid < NB_TN) {
        A = tn_in; Wp = W;                 Cout = tn_out; M = M_TN; addb = false; local = bid;
    } else {
        A = pn_in; Wp = W + DIM_H * DIM_O; Cout = pn_out; M = M_PN; addb = true;  local = bid - NB_TN;
    }
    const int bm = local / NB_N;
    const int bn = local - bm * NB_N;
    const int row0 = bm * 64;
    const int col0 = bn * 64;

    __shared__ float As[BK][68];   // transposed [k][row], pad 68 (2-way = free)
    __shared__ float Bs[BK][64];

    const int tid = threadIdx.x;
    const int ty = tid >> 4, tx = tid & 15;
    const int ar = tid >> 2, ac = (tid & 3) << 3;
    const int br = tid >> 3, bc = (tid & 7) << 3;

    float acc[4][4];
    #pragma unroll
    for (int i = 0; i < 4; ++i)
        #pragma unroll
        for (int j = 0; j < 4; ++j) acc[i][j] = 0.f;

    const int gr = row0 + ar;
    const bool arow_ok = (gr < M);
    const float* __restrict__ Arow = A + (size_t)gr * DIM_H;
    const float* __restrict__ Bbase = Wp + col0;

    f32x4 a0 = 0.f, a1 = 0.f, b0, b1;
    if (arow_ok) {
        a0 = *(const f32x4*)(Arow + ac);
        a1 = *(const f32x4*)(Arow + ac + 4);
    }
    b0 = *(const f32x4*)(Bbase + (size_t)br * DIM_O + bc);
    b1 = *(const f32x4*)(Bbase + (size_t)br * DIM_O + bc + 4);

    for (int k0 = 0; k0 < DIM_H; k0 += BK) {
        __syncthreads();
        #pragma unroll
        for (int j = 0; j < 4; ++j) {
            As[ac + j][ar]     = a0[j];
            As[ac + 4 + j][ar] = a1[j];
        }
        *(f32x4*)&Bs[br][bc]     = b0;
        *(f32x4*)&Bs[br][bc + 4] = b1;
        __syncthreads();

        const int kn = k0 + BK;
        if (kn < DIM_H) {
            if (arow_ok) {
                a0 = *(const f32x4*)(Arow + kn + ac);
                a1 = *(const f32x4*)(Arow + kn + ac + 4);
            }
            b0 = *(const f32x4*)(Bbase + (size_t)(kn + br) * DIM_O + bc);
            b1 = *(const f32x4*)(Bbase + (size_t)(kn + br) * DIM_O + bc + 4);
        }

        #pragma unroll
        for (int kk = 0; kk < BK; ++kk) {
            const f32x4 a = *(const f32x4*)&As[kk][ty << 2];
            const f32x4 b = *(const f32x4*)&Bs[kk][tx << 2];
            #pragma unroll
            for (int i = 0; i < 4; ++i) {
                acc[i][0] = fmaf(a[i], b[0], acc[i][0]);
                acc[i][1] = fmaf(a[i], b[1], acc[i][1]);
                acc[i][2] = fmaf(a[i], b[2], acc[i][2]);
                acc[i][3] = fmaf(a[i], b[3], acc[i][3]);
            }
        }
    }

    f32x4 bsv = 0.f;
    if (addb) bsv = *(const f32x4*)(bias + col0 + (tx << 2));
    #pragma unroll
    for (int i = 0; i < 4; ++i) {
        const int r = row0 + (ty << 2) + i;
        if (r < M) {
            f32x4 v;
            #pragma unroll
            for (int j = 0; j < 4; ++j) v[j] = acc[i][j] + bsv[j];
            *(f32x4*)(Cout + (size_t)r * DIM_O + col0 + (tx << 2)) = v;
        }
    }
}

// Joint v3: fully-resident grid-stride. 2048 blocks x 256 thr (8 blk/CU, trivial
// VGPR), no LDS/sync. idx walks all 30.72M f32x4 outputs; per iter 3 const-divisor
// magic-muls, two L2-hit 16B reads (tn value re-read 80x time-locally; pn panels
// 1.64 MB total, L2-resident, NT writes never evict them), one NT 16B store.
__global__ __launch_bounds__(256) void joint_kernel(
    const float* __restrict__ tn_proj,   // M_TN x O
    const float* __restrict__ pn_proj,   // M_PN x O (bias pre-added)
    float* __restrict__ out)
{
    const f32x4* __restrict__ tn4 = (const f32x4*)tn_proj;
    const f32x4* __restrict__ pn4 = (const f32x4*)pn_proj;
    f32x4* __restrict__ out4 = (f32x4*)out;

    const unsigned total = 30720000u;            // 2400*80*160
    const unsigned stride = 2048u * 256u;        // 524288, all resident
    for (unsigned idx = blockIdx.x * 256u + threadIdx.x; idx < total; idx += stride) {
        const unsigned bt  = idx / 12800u;       // 80*160
        const unsigned rem = idx - bt * 12800u;
        const unsigned b   = bt / 300u;
        const unsigned o4  = rem % 160u;
        const f32x4 t = tn4[bt * 160u + o4];
        const f32x4 p = pn4[b * 12800u + rem];
        f32x4 r;
        #pragma unroll
        for (int j = 0; j < 4; ++j) {
            const float x = t[j] + p[j];
            r[j] = fmaxf(x, 0.f) + NEG_SLOPE * fminf(x, 0.f);
        }
        __builtin_nontemporal_store(r, &out4[idx]);
    }
}

extern "C" void kernel_launch(void* const* d_in, const int* in_sizes, int n_in,
                              void* d_out, int out_size, void* d_ws, size_t ws_size,
                              hipStream_t stream) {
    const float* tn   = (const float*)d_in[0];   // (8,300,1,512)
    const float* pn   = (const float*)d_in[1];   // (8,1,80,512)
    const float* W    = (const float*)d_in[2];   // (1024,640)
    const float* bias = (const float*)d_in[3];   // (640,)
    float* out = (float*)d_out;

    float* tn_proj = (float*)d_ws;                       // 2400*640 fp32 = 6.14 MB
    float* pn_proj = tn_proj + (size_t)M_TN * DIM_O;     // 640*640 fp32 = 1.64 MB

    proj_gemm<<<NB_TN + NB_PN, 256, 0, stream>>>(tn, pn, W, bias, tn_proj, pn_proj);
    joint_kernel<<<2048, 256, 0, stream>>>(tn_proj, pn_proj, out);
}